// Round 9
// baseline (88.345 us; speedup 1.0000x reference)
//
#include <hip/hip_runtime.h>

namespace {

constexpr int HIMG = 512;
constexpr int ROWF = 512 * 3;            // 1536 floats per image row
constexpr int NT   = 384;                // one float4 column per thread
constexpr int RCH  = 4;                  // rows per chunk
constexpr int NLOAD = RCH + 6;           // 10 rows for chunk A
constexpr int HALO = 12;                 // halo floats each side (16B aligned)
constexpr int RP   = HALO + ROWF + HALO; // 1560 floats per LDS row
constexpr int PAIRS = HIMG / (2 * RCH);  // 64 chunk-pairs per image

typedef float vf4 __attribute__((ext_vector_type(4)));

// exp(-x^2/(2*1.5^2)), double precision (matches cv2.getGaussianKernel)
constexpr double KD0 = 0.13533528323661270;  // x=3
constexpr double KD1 = 0.41111229050718745;  // x=2
constexpr double KD2 = 0.80073740291680804;  // x=1
constexpr double KSUM = 1.0 + 2.0 * (KD0 + KD1 + KD2);

__global__ __launch_bounds__(NT, 5) void gauss7(const float* __restrict__ in,
                                                float* __restrict__ out) {
  constexpr float W[7] = {
      (float)(KD0 / KSUM), (float)(KD1 / KSUM), (float)(KD2 / KSUM),
      (float)(1.0 / KSUM),
      (float)(KD2 / KSUM), (float)(KD1 / KSUM), (float)(KD0 / KSUM)};

  __shared__ __align__(16) float lds[RCH][RP];

  // bijective XCD swizzle: 4096 blocks, 8 XCDs -> XCD k owns contiguous 512
  const int bid = blockIdx.x;
  const int b   = (bid & 7) * (PAIRS * 64 / 8) + (bid >> 3);

  const int n  = b >> 6;        // image index (64 pairs per image)
  const int pc = b & 63;
  const int h0 = pc * 2 * RCH;  // first output row of chunk A
  const int t  = threadIdx.x;

  const float* inN  = in  + (size_t)n * HIMG * ROWF;
  float*       outN = out + (size_t)n * HIMG * ROWF;
  const float4* inCol = reinterpret_cast<const float4*>(inN) + t;

  // ---- stage helper: LDS write + verified reflect-101 W-halo scatter ----
  auto stage = [&](const float4* a) {
#pragma unroll
    for (int i = 0; i < RCH; ++i) {
      const float4 v = a[i];
      float* lrow = &lds[i][HALO];
      *reinterpret_cast<float4*>(lrow + 4 * t) = v;
      if (t == 0) {                  // floats 0..3
        lrow[-3] = v.w;
      } else if (t == 1) {           // floats 4..7
        lrow[-2] = v.x; lrow[-1] = v.y; lrow[-6] = v.z; lrow[-5] = v.w;
      } else if (t == 2) {           // floats 8..11
        lrow[-4] = v.x; lrow[-9] = v.y; lrow[-8] = v.z; lrow[-7] = v.w;
      } else if (t == NT - 3) {      // floats 1524..1527
        lrow[1542] = v.x; lrow[1543] = v.y; lrow[1544] = v.z; lrow[1539] = v.w;
      } else if (t == NT - 2) {      // floats 1528..1531
        lrow[1540] = v.x; lrow[1541] = v.y; lrow[1536] = v.z; lrow[1537] = v.w;
      } else if (t == NT - 1) {      // floats 1532..1535
        lrow[1538] = v.x;
      }
    }
  };

  // ---- horizontal pass (R6-verified): 7 x b128 window, 4 rows, nt stores ----
  auto horiz = [&](int hbase) {
#pragma unroll
    for (int k = 0; k < RCH; ++k) {
      const float* rowp = &lds[k][HALO + 4 * t - 12];
      float s[28];
#pragma unroll
      for (int j = 0; j < 7; ++j)
        *reinterpret_cast<float4*>(&s[4 * j]) =
            *reinterpret_cast<const float4*>(rowp + 4 * j);
      vf4 o;
#pragma unroll
      for (int m = 0; m < 4; ++m)
        o[m] = W[0]*s[m+3]  + W[1]*s[m+6]  + W[2]*s[m+9]  + W[3]*s[m+12] +
               W[4]*s[m+15] + W[5]*s[m+18] + W[6]*s[m+21];
      __builtin_nontemporal_store(
          o, reinterpret_cast<vf4*>(outN + (size_t)(hbase + k) * ROWF) + t);
    }
  };

  // ---- chunk A: load rows h0-3 .. h0+6 ----
  float4 rw[NLOAD];
#pragma unroll
  for (int i = 0; i < NLOAD; ++i) {
    int r  = h0 - 3 + i;
    int rr = r < 0 ? -r : (r > HIMG - 1 ? 2 * (HIMG - 1) - r : r);
    rw[i]  = inCol[(size_t)rr * NT];
  }

  float4 acc[RCH];
#pragma unroll
  for (int o = 0; o < RCH; ++o) acc[o] = make_float4(0.f, 0.f, 0.f, 0.f);
#pragma unroll
  for (int i = 0; i < NLOAD; ++i) {
#pragma unroll
    for (int o = 0; o < RCH; ++o) {
      if (i >= o && i <= o + 6) {
        const float w = W[i - o];
        acc[o].x += w * rw[i].x;
        acc[o].y += w * rw[i].y;
        acc[o].z += w * rw[i].z;
        acc[o].w += w * rw[i].w;
      }
    }
  }

  // ---- chunk B prefetch: rows h0+7 .. h0+10 into rw[0..3] (A no longer needs them)
  // latency hides under stage A + barrier + horizontal A.
#pragma unroll
  for (int i = 0; i < 4; ++i) {
    int r  = h0 + 7 + i;
    int rr = r > HIMG - 1 ? 2 * (HIMG - 1) - r : r;
    rw[i]  = inCol[(size_t)rr * NT];
  }

  stage(acc);
  __syncthreads();
  horiz(h0);                 // stores rows h0..h0+3 while B loads are in flight
  __syncthreads();           // lds reads done before restaging

  // ---- chunk B: logical row (h0+1+m) lives in rw[(m+4) % 10] ----
  // output row o (abs h0+4+o) taps logical m = o..o+6 with weight W[m-o]
  // -> identical ascending summation order as chunk A.
#pragma unroll
  for (int o = 0; o < RCH; ++o) acc[o] = make_float4(0.f, 0.f, 0.f, 0.f);
#pragma unroll
  for (int m = 0; m < NLOAD; ++m) {
    const float4 rv = rw[(m + 4) % NLOAD];
#pragma unroll
    for (int o = 0; o < RCH; ++o) {
      if (m >= o && m <= o + 6) {
        const float w = W[m - o];
        acc[o].x += w * rv.x;
        acc[o].y += w * rv.y;
        acc[o].z += w * rv.z;
        acc[o].w += w * rv.w;
      }
    }
  }

  stage(acc);
  __syncthreads();
  horiz(h0 + RCH);           // stores rows h0+4..h0+7
}

}  // namespace

extern "C" void kernel_launch(void* const* d_in, const int* in_sizes, int n_in,
                              void* d_out, int out_size, void* d_ws, size_t ws_size,
                              hipStream_t stream) {
  const float* x = (const float*)d_in[0];
  float*       y = (float*)d_out;
  dim3 grid(64 * PAIRS);   // 4096 blocks
  dim3 block(NT);
  hipLaunchKernelGGL(gauss7, grid, block, 0, stream, x, y);
}

// Round 10
// 62.845 us; speedup vs baseline: 1.4058x; 1.4058x over previous
//
#include <hip/hip_runtime.h>

namespace {

constexpr int HIMG = 512;
constexpr int ROWF = 512 * 3;            // 1536 floats per image row
constexpr int NT   = 384;                // one float4 column per thread
constexpr int RCH  = 4;                  // output rows per block
constexpr int NLOAD = RCH + 6;           // 10 input rows per block
constexpr int HALO = 12;                 // halo floats each side (16B aligned)
constexpr int RP   = HALO + ROWF + HALO; // 1560 floats per LDS row
constexpr int CHUNKS = HIMG / RCH;       // 128 chunks per image

typedef float vf4 __attribute__((ext_vector_type(4)));

// exp(-x^2/(2*1.5^2)), double precision (matches cv2.getGaussianKernel)
constexpr double KD0 = 0.13533528323661270;  // x=3
constexpr double KD1 = 0.41111229050718745;  // x=2
constexpr double KD2 = 0.80073740291680804;  // x=1
constexpr double KSUM = 1.0 + 2.0 * (KD0 + KD1 + KD2);

__global__ __launch_bounds__(NT, 6) void gauss7(const float* __restrict__ in,
                                                float* __restrict__ out) {
  constexpr float W[7] = {
      (float)(KD0 / KSUM), (float)(KD1 / KSUM), (float)(KD2 / KSUM),
      (float)(1.0 / KSUM),
      (float)(KD2 / KSUM), (float)(KD1 / KSUM), (float)(KD0 / KSUM)};

  __shared__ __align__(16) float lds[RCH][RP];

  // bijective XCD swizzle: 8192 blocks, 8 XCDs -> XCD k owns contiguous 1024
  // (vertically-neighboring chunks share 6 halo rows -> L2/L3 hits)
  const int bid = blockIdx.x;
  const int b   = (bid & 7) * (CHUNKS * 64 / 8) + (bid >> 3);

  const int n  = b >> 7;        // image index (128 chunks per image)
  const int hc = b & 127;
  const int h0 = hc * RCH;
  const int t  = threadIdx.x;

  const float* inN  = in  + (size_t)n * HIMG * ROWF;
  float*       outN = out + (size_t)n * HIMG * ROWF;
  const float4* inCol = reinterpret_cast<const float4*>(inN) + t;  // row stride = 384 float4

  // ---- 10 row loads (reflect-101 in H) ----
  float4 rw[NLOAD];
#pragma unroll
  for (int i = 0; i < NLOAD; ++i) {
    int r  = h0 - 3 + i;
    int rr = r < 0 ? -r : (r > HIMG - 1 ? 2 * (HIMG - 1) - r : r);
    rw[i]  = inCol[(size_t)rr * NT];
  }

  // ---- vertical blur 4 rows -> LDS ----
#pragma unroll
  for (int i = 0; i < RCH; ++i) {
    float4 v;
    v.x = W[0]*rw[i].x + W[1]*rw[i+1].x + W[2]*rw[i+2].x + W[3]*rw[i+3].x +
          W[4]*rw[i+4].x + W[5]*rw[i+5].x + W[6]*rw[i+6].x;
    v.y = W[0]*rw[i].y + W[1]*rw[i+1].y + W[2]*rw[i+2].y + W[3]*rw[i+3].y +
          W[4]*rw[i+4].y + W[5]*rw[i+5].y + W[6]*rw[i+6].y;
    v.z = W[0]*rw[i].z + W[1]*rw[i+1].z + W[2]*rw[i+2].z + W[3]*rw[i+3].z +
          W[4]*rw[i+4].z + W[5]*rw[i+5].z + W[6]*rw[i+6].z;
    v.w = W[0]*rw[i].w + W[1]*rw[i+1].w + W[2]*rw[i+2].w + W[3]*rw[i+3].w +
          W[4]*rw[i+4].w + W[5]*rw[i+5].w + W[6]*rw[i+6].w;

    float* lrow = &lds[i][HALO];
    *reinterpret_cast<float4*>(lrow + 4 * t) = v;   // 16B-aligned, conflict-free

    // reflect-101 W-halo scatter (verified mapping, R2/R4/R5)
    if (t == 0) {                  // floats 0..3
      lrow[-3] = v.w;              // f3  (p1,c0) -> -3
    } else if (t == 1) {           // floats 4..7
      lrow[-2] = v.x; lrow[-1] = v.y; lrow[-6] = v.z; lrow[-5] = v.w;
    } else if (t == 2) {           // floats 8..11
      lrow[-4] = v.x; lrow[-9] = v.y; lrow[-8] = v.z; lrow[-7] = v.w;
    } else if (t == NT - 3) {      // floats 1524..1527
      lrow[1542] = v.x; lrow[1543] = v.y; lrow[1544] = v.z; lrow[1539] = v.w;
    } else if (t == NT - 2) {      // floats 1528..1531
      lrow[1540] = v.x; lrow[1541] = v.y; lrow[1536] = v.z; lrow[1537] = v.w;
    } else if (t == NT - 1) {      // floats 1532..1535
      lrow[1538] = v.x;
    }
  }
  __syncthreads();

  // ---- horizontal pass: thread t -> output floats 4t..4t+3 of each row ----
  // window: floats 4t-12 .. 4t+15 (28 floats, 7 x b128, 16B/lane contiguous)
#pragma unroll
  for (int k = 0; k < RCH; ++k) {
    const float* rowp = &lds[k][HALO + 4 * t - 12];
    float s[28];
#pragma unroll
    for (int j = 0; j < 7; ++j)
      *reinterpret_cast<float4*>(&s[4 * j]) =
          *reinterpret_cast<const float4*>(rowp + 4 * j);
    // out[4t+m] taps: s[m+3], s[m+6], ..., s[m+21]
    vf4 o;
#pragma unroll
    for (int m = 0; m < 4; ++m)
      o[m] = W[0]*s[m+3]  + W[1]*s[m+6]  + W[2]*s[m+9]  + W[3]*s[m+12] +
             W[4]*s[m+15] + W[5]*s[m+18] + W[6]*s[m+21];
    // non-temporal: output is never re-read; keep input resident in L2/L3
    vf4* orow = reinterpret_cast<vf4*>(outN + (size_t)(h0 + k) * ROWF);
    __builtin_nontemporal_store(o, orow + t);
  }
}

}  // namespace

extern "C" void kernel_launch(void* const* d_in, const int* in_sizes, int n_in,
                              void* d_out, int out_size, void* d_ws, size_t ws_size,
                              hipStream_t stream) {
  const float* x = (const float*)d_in[0];
  float*       y = (float*)d_out;
  dim3 grid(64 * CHUNKS);   // 8192 blocks
  dim3 block(NT);
  hipLaunchKernelGGL(gauss7, grid, block, 0, stream, x, y);
}